// Round 1
// baseline (806.941 us; speedup 1.0000x reference)
//
#include <hip/hip_runtime.h>
#include <stdint.h>

typedef short short8 __attribute__((ext_vector_type(8)));
typedef short short4v __attribute__((ext_vector_type(4)));
typedef float floatx4 __attribute__((ext_vector_type(4)));

#define H_  8
#define NB_ 4      // batch N
#define S_  1024
#define D_  512
#define KD_ 64

__device__ __forceinline__ short f2bf(float f){
    unsigned u = __builtin_bit_cast(unsigned, f);
    u += 0x7fffu + ((u>>16)&1u);
    return (short)(u>>16);
}
__device__ __forceinline__ float wred_addf(float x){
    #pragma unroll
    for(int o=32;o>0;o>>=1) x += __shfl_xor(x,o,64);
    return x;
}
__device__ __forceinline__ float wred_maxf(float x){
    #pragma unroll
    for(int o=32;o>0;o>>=1) x = fmaxf(x,__shfl_xor(x,o,64));
    return x;
}
__device__ __forceinline__ int wred_addi(int x){
    #pragma unroll
    for(int o=32;o>0;o>>=1) x += __shfl_xor(x,o,64);
    return x;
}

// ---------------- elementwise fp32 -> bf16 ----------------
__global__ __launch_bounds__(256) void cvt_bf16_kernel(const float* __restrict__ in,
                                                       short* __restrict__ out, int n){
    int i = (blockIdx.x*256 + threadIdx.x)*4;
    if (i + 3 < n){
        floatx4 v = *(const floatx4*)(in + i);
        short4v r;
        #pragma unroll
        for(int j=0;j<4;j++) r[j] = f2bf(v[j]);
        *(short4v*)(out + i) = r;
    }
}

// ---------------- weight transpose + convert: in [R][C] f32 -> out [C][R] bf16 ----------------
__global__ __launch_bounds__(256) void wtrans_kernel(const float* __restrict__ in, short* __restrict__ out,
                                                     int R, int C, long inB, long outB){
    __shared__ float t[32][33];
    int z = blockIdx.z;
    const float* ip = in + (long)z*inB;
    short* op = out + (long)z*outB;
    int c0 = blockIdx.x*32, r0 = blockIdx.y*32;
    int tid = threadIdx.x;
    int r = tid>>3, cq = (tid&7)*4;
    #pragma unroll
    for(int i=0;i<4;i++) t[r][cq+i] = ip[(long)(r0+r)*C + c0+cq+i];
    __syncthreads();
    int c = tid>>3, rq = (tid&7)*4;
    #pragma unroll
    for(int i=0;i<4;i++) op[(long)(c0+c)*R + r0+rq+i] = f2bf(t[rq+i][c]);
}

// ---------------- row softmax of the two graphs ----------------
__global__ __launch_bounds__(256) void graph_softmax_kernel(const float* __restrict__ g0,
                                                            const float* __restrict__ g1,
                                                            float* __restrict__ o0,
                                                            float* __restrict__ o1){
    int row = blockIdx.x;
    const float* g = blockIdx.y ? g1 : g0;
    float* o = blockIdx.y ? o1 : o0;
    const float* gr = g + (long)row*S_;
    float* orow = o + (long)row*S_;
    int tid = threadIdx.x, wave = tid>>6, lane = tid&63;
    __shared__ float red[8];
    float v[4]; float mx = -3.0e38f;
    #pragma unroll
    for(int i=0;i<4;i++){ v[i] = gr[tid + 256*i]; mx = fmaxf(mx, v[i]); }
    mx = wred_maxf(mx);
    if(lane==0) red[wave] = mx;
    __syncthreads();
    mx = fmaxf(fmaxf(red[0],red[1]), fmaxf(red[2],red[3]));
    float s = 0.f;
    #pragma unroll
    for(int i=0;i<4;i++){ v[i] = __expf(v[i]-mx); s += v[i]; }
    s = wred_addf(s);
    if(lane==0) red[4+wave] = s;
    __syncthreads();
    s = red[4]+red[5]+red[6]+red[7];
    float inv = 1.f/s;
    #pragma unroll
    for(int i=0;i<4;i++) orow[tid + 256*i] = v[i]*inv;
}

// ---------------- generic bf16 MFMA GEMM: C = A[MxK] * Bt[NxK]^T + bias ----------------
// mode 0: f32 out [M][N];  1: bf16 out [M][N]
// mode 2: bf16 K/Q layout out[((z*4 + m>>10)*1024 + (m&1023))*64 + n]   (N==64)
// mode 3: bf16 Vt layout  out[((z*4 + m>>10)*64 + n)*1024 + (m&1023)]  (N==64)
__global__ __launch_bounds__(256) void gemm_kernel(
    const short* __restrict__ A, const short* __restrict__ Bt, const float* __restrict__ bias,
    void* __restrict__ out, int M, int N, int K,
    long batchA, long batchB, long batchBias, int mode, int relu)
{
    int z = blockIdx.z;
    const short* Ab = A + (long)z*batchA;
    const short* Bb = Bt + (long)z*batchB;
    const float* bb = bias + (long)z*batchBias;
    int m0 = blockIdx.x*64, n0 = blockIdx.y*64;
    int tid = threadIdx.x, wave = tid>>6, lane = tid&63;
    int quad = lane>>4, nl = lane&15;
    int wm = (wave&1)*32, wn = (wave>>1)*32;
    floatx4 acc[2][2];
    #pragma unroll
    for(int i=0;i<2;i++)
        #pragma unroll
        for(int j=0;j<2;j++) acc[i][j] = (floatx4){0.f,0.f,0.f,0.f};

    const short* Aptr0 = Ab + (long)(m0 + wm + nl)*K + quad*8;
    const short* Aptr1 = Aptr0 + 16*(long)K;
    const short* Bptr0 = Bb + (long)(n0 + wn + nl)*K + quad*8;
    const short* Bptr1 = Bptr0 + 16*(long)K;

    for(int k0=0;k0<K;k0+=32){
        short8 a0 = *(const short8*)(Aptr0 + k0);
        short8 a1 = *(const short8*)(Aptr1 + k0);
        short8 b0 = *(const short8*)(Bptr0 + k0);
        short8 b1 = *(const short8*)(Bptr1 + k0);
        acc[0][0] = __builtin_amdgcn_mfma_f32_16x16x32_bf16(a0,b0,acc[0][0],0,0,0);
        acc[0][1] = __builtin_amdgcn_mfma_f32_16x16x32_bf16(a0,b1,acc[0][1],0,0,0);
        acc[1][0] = __builtin_amdgcn_mfma_f32_16x16x32_bf16(a1,b0,acc[1][0],0,0,0);
        acc[1][1] = __builtin_amdgcn_mfma_f32_16x16x32_bf16(a1,b1,acc[1][1],0,0,0);
    }
    #pragma unroll
    for(int i=0;i<2;i++){
        #pragma unroll
        for(int j=0;j<2;j++){
            int n = n0 + wn + j*16 + nl;
            float bv = bb[n];
            #pragma unroll
            for(int r=0;r<4;r++){
                int m = m0 + wm + i*16 + quad*4 + r;
                float v = acc[i][j][r] + bv;
                if(relu) v = fmaxf(v, 0.f);
                if(mode==0)      ((float*)out)[(long)m*N + n] = v;
                else if(mode==1) ((short*)out)[(long)m*N + n] = f2bf(v);
                else if(mode==2) ((short*)out)[ ((long)(z*NB_ + (m>>10))*S_ + (m&1023))*KD_ + n ] = f2bf(v);
                else             ((short*)out)[ ((long)(z*NB_ + (m>>10))*KD_ + n)*S_ + (m&1023) ] = f2bf(v);
            }
        }
    }
}

// ---------------- fused attention ----------------
// Qb/Kb: bf16 [HN][S][64]; Vt: bf16 [HN][64][S]; graph: softmaxed [S][S] f32
// ctx out: bf16 [(n*S + q)*512 + h*64 + v]
// scores LDS rows rotated by 8*q floats (bank-conflict swizzle, 8-aligned so b128 never wraps)
__global__ __launch_bounds__(256) void attn_kernel(
    const short* __restrict__ Qb, const short* __restrict__ Kb, const short* __restrict__ Vt,
    const float* __restrict__ graph, short* __restrict__ ctx, int causal)
{
    __shared__ float sc[16*1024];   // 64 KiB
    int qt = blockIdx.x, hn = blockIdx.y;
    int h = hn>>2, n = hn&3;
    int q0 = qt*16;
    int tid=threadIdx.x, wave=tid>>6, lane=tid&63, quad=lane>>4, nl=lane&15;

    // ---- phase 1: scores = Q K^T / 8 into LDS ----
    const short* Qp = Qb + ((long)hn*S_ + q0 + nl)*KD_ + quad*8;
    short8 aq0 = *(const short8*)(Qp);
    short8 aq1 = *(const short8*)(Qp + 32);
    const short* Kp = Kb + (long)hn*S_*KD_;
    int stmax = causal ? qt : 63;
    for(int st=wave; st<=stmax; st+=4){
        const short* kp = Kp + (st*16 + nl)*KD_ + quad*8;
        short8 b0 = *(const short8*)(kp);
        short8 b1 = *(const short8*)(kp + 32);
        floatx4 c = (floatx4){0.f,0.f,0.f,0.f};
        c = __builtin_amdgcn_mfma_f32_16x16x32_bf16(aq0,b0,c,0,0,0);
        c = __builtin_amdgcn_mfma_f32_16x16x32_bf16(aq1,b1,c,0,0,0);
        #pragma unroll
        for(int r=0;r<4;r++){
            int q = quad*4 + r, s = st*16 + nl;
            sc[q*1024 + ((s + q*8)&1023)] = c[r]*0.125f;
        }
    }
    __syncthreads();

    // ---- phase 2: per-row top-128 threshold (exact), softmax, graph blend ----
    for(int rr=0; rr<4; rr++){
        int q = wave*4 + rr;
        int qg = q0 + q;
        int slimit = causal ? qg : 1023;
        float v[16]; unsigned mv[16];
        float mx = -3.0e38f;
        #pragma unroll
        for(int j=0;j<16;j++){
            int s = lane + 64*j;
            float x = (s<=slimit) ? sc[q*1024 + ((s + q*8)&1023)] : -__builtin_inff();
            v[j] = x;
            mx = fmaxf(mx, x);
            unsigned u = __builtin_bit_cast(unsigned, x);
            mv[j] = (u>>31) ? ~u : (u | 0x80000000u);
        }
        mx = wred_maxf(mx);
        unsigned um = __builtin_bit_cast(unsigned, mx);
        um = (um>>31) ? ~um : (um | 0x80000000u);
        unsigned lo = 0u, hi = um + 1u;
        while(hi - lo > 1u){
            unsigned mid = lo + ((hi - lo)>>1);
            int c = 0;
            #pragma unroll
            for(int j=0;j<16;j++) c += (mv[j] >= mid) ? 1 : 0;
            c = wred_addi(c);
            if(c >= 128){ lo = mid; if(c == 128) break; }
            else hi = mid;
        }
        unsigned thr = lo;
        float sum = 0.f; float e[16];
        #pragma unroll
        for(int j=0;j<16;j++){
            e[j] = (mv[j] >= thr) ? __expf(v[j]-mx) : 0.f;
            sum += e[j];
        }
        sum = wred_addf(sum);
        float inv = 0.5f / sum;   // (1-gw) = 0.5
        const float* grow = graph + (long)qg*S_;
        #pragma unroll
        for(int j=0;j<16;j++){
            int s = lane + 64*j;
            float a = 0.5f*grow[s] + e[j]*inv;   // graph part NOT causally masked
            sc[q*1024 + ((s + q*8)&1023)] = a;
        }
    }
    __syncthreads();

    // ---- phase 3: ctx = att @ V  (full s-range; graph part everywhere) ----
    int v0 = wave*16;
    const short* Vp = Vt + ((long)hn*KD_ + v0 + nl)*S_;
    floatx4 o4 = (floatx4){0.f,0.f,0.f,0.f};
    int qrow = nl;
    for(int s0=0; s0<1024; s0+=32){
        int cs = (s0 + quad*8 + qrow*8) & 1023;
        floatx4 p0 = *(floatx4*)(&sc[qrow*1024 + cs]);
        floatx4 p1 = *(floatx4*)(&sc[qrow*1024 + cs + 4]);
        short8 ap;
        #pragma unroll
        for(int j=0;j<4;j++){ ap[j] = f2bf(p0[j]); ap[j+4] = f2bf(p1[j]); }
        short8 bv = *(const short8*)(Vp + s0 + quad*8);
        o4 = __builtin_amdgcn_mfma_f32_16x16x32_bf16(ap,bv,o4,0,0,0);
    }
    #pragma unroll
    for(int r=0;r<4;r++){
        int q = quad*4 + r;
        ctx[ ((long)(n*S_ + q0 + q))*512 + h*KD_ + v0 + nl ] = f2bf(o4[r]);
    }
}

// ---------------- LayerNorm(x + res), optional f32 + bf16 outputs ----------------
__global__ __launch_bounds__(256) void ln_kernel(const float* __restrict__ x, const float* __restrict__ res,
                                                 float* __restrict__ outf, short* __restrict__ outb){
    long row = blockIdx.x;
    const float* xr = x + row*D_;
    const float* rr = res + row*D_;
    int tid = threadIdx.x, wave = tid>>6, lane = tid&63;
    float t0 = xr[tid] + rr[tid];
    float t1 = xr[tid+256] + rr[tid+256];
    float s = t0 + t1, s2 = t0*t0 + t1*t1;
    __shared__ float red[8];
    s = wred_addf(s); s2 = wred_addf(s2);
    if(lane==0){ red[wave] = s; red[4+wave] = s2; }
    __syncthreads();
    s  = red[0]+red[1]+red[2]+red[3];
    s2 = red[4]+red[5]+red[6]+red[7];
    float mean = s*(1.f/512.f);
    float var = s2*(1.f/512.f) - mean*mean;
    float rs = rsqrtf(var + 1e-5f);
    float o0 = (t0-mean)*rs, o1 = (t1-mean)*rs;
    if(outf){ outf[row*D_+tid] = o0; outf[row*D_+tid+256] = o1; }
    if(outb){ outb[row*D_+tid] = f2bf(o0); outb[row*D_+tid+256] = f2bf(o1); }
}

extern "C" void kernel_launch(void* const* d_in, const int* in_sizes, int n_in,
                              void* d_out, int out_size, void* d_ws, size_t ws_size,
                              hipStream_t stream)
{
    const float* z         = (const float*)d_in[0];
    const float* y         = (const float*)d_in[1];
    const float* graph_dec = (const float*)d_in[2];
    const float* graph_enc = (const float*)d_in[3];
    const float* dec_Wk = (const float*)d_in[4];  const float* dec_bk = (const float*)d_in[5];
    const float* dec_Wv = (const float*)d_in[6];  const float* dec_bv = (const float*)d_in[7];
    const float* dec_Wo = (const float*)d_in[8];  const float* dec_bo = (const float*)d_in[9];
    const float* enc_Wk = (const float*)d_in[10]; const float* enc_bk = (const float*)d_in[11];
    const float* enc_Wq = (const float*)d_in[12]; const float* enc_bq = (const float*)d_in[13];
    const float* enc_Wv = (const float*)d_in[14]; const float* enc_bv = (const float*)d_in[15];
    const float* enc_Wo = (const float*)d_in[16]; const float* enc_bo = (const float*)d_in[17];
    const float* fc_W1  = (const float*)d_in[18]; const float* fc_b1  = (const float*)d_in[19];
    const float* fc_W2  = (const float*)d_in[20]; const float* fc_b2  = (const float*)d_in[21];

    char* ws = (char*)d_ws;
    float* gdec  = (float*)(ws + 0x0000000);
    float* genc  = (float*)(ws + 0x0400000);
    short* y_bf  = (short*)(ws + 0x0800000);
    short* z_bf  = (short*)(ws + 0x0C00000);
    short* Kdec  = (short*)(ws + 0x1000000);
    short* Vtdec = (short*)(ws + 0x1400000);
    short* Kenc  = (short*)(ws + 0x1800000);
    short* Vtenc = (short*)(ws + 0x1C00000);
    short* Qenc  = (short*)(ws + 0x2000000);
    short* ctx   = (short*)(ws + 0x2400000);
    float* tmp   = (float*)(ws + 0x2800000);
    float* hbuf  = (float*)(ws + 0x3000000);
    short* h_bf  = (short*)(ws + 0x3800000);
    float* h2    = (float*)(ws + 0x3C00000);
    short* h2_bf = (short*)(ws + 0x4400000);
    short* fc1   = (short*)(ws + 0x4800000);
    short* wKdt  = (short*)(ws + 0x5800000);
    short* wVdt  = (short*)(ws + 0x5880000);
    short* wOdt  = (short*)(ws + 0x5900000);
    short* wKet  = (short*)(ws + 0x5980000);
    short* wQet  = (short*)(ws + 0x5A00000);
    short* wVet  = (short*)(ws + 0x5A80000);
    short* wOet  = (short*)(ws + 0x5B00000);
    short* wF1t  = (short*)(ws + 0x5B80000);
    short* wF2t  = (short*)(ws + 0x5D80000);
    float* outp  = (float*)d_out;

    dim3 B(256);
    // weight transposes -> bf16 [N][K]
    wtrans_kernel<<<dim3(2,16,8),  B,0,stream>>>(dec_Wk, wKdt, 512,  64, 512*64, 64*512);
    wtrans_kernel<<<dim3(2,16,8),  B,0,stream>>>(dec_Wv, wVdt, 512,  64, 512*64, 64*512);
    wtrans_kernel<<<dim3(16,16,1), B,0,stream>>>(dec_Wo, wOdt, 512, 512, 0, 0);
    wtrans_kernel<<<dim3(2,16,8),  B,0,stream>>>(enc_Wk, wKet, 512,  64, 512*64, 64*512);
    wtrans_kernel<<<dim3(2,16,8),  B,0,stream>>>(enc_Wq, wQet, 512,  64, 512*64, 64*512);
    wtrans_kernel<<<dim3(2,16,8),  B,0,stream>>>(enc_Wv, wVet, 512,  64, 512*64, 64*512);
    wtrans_kernel<<<dim3(16,16,1), B,0,stream>>>(enc_Wo, wOet, 512, 512, 0, 0);
    wtrans_kernel<<<dim3(64,16,1), B,0,stream>>>(fc_W1,  wF1t, 512,2048, 0, 0);
    wtrans_kernel<<<dim3(16,64,1), B,0,stream>>>(fc_W2,  wF2t,2048, 512, 0, 0);
    // activation converts
    cvt_bf16_kernel<<<dim3(2048),B,0,stream>>>(y, y_bf, 2097152);
    cvt_bf16_kernel<<<dim3(2048),B,0,stream>>>(z, z_bf, 2097152);
    // graph softmax
    graph_softmax_kernel<<<dim3(1024,2),B,0,stream>>>(graph_dec, graph_enc, gdec, genc);
    // decoder stage
    gemm_kernel<<<dim3(64,1,8),B,0,stream>>>(y_bf, wKdt, dec_bk, Kdec,  4096,  64,  512, 0, 64*512, 64, 2, 0);
    gemm_kernel<<<dim3(64,1,8),B,0,stream>>>(y_bf, wVdt, dec_bv, Vtdec, 4096,  64,  512, 0, 64*512, 64, 3, 0);
    attn_kernel<<<dim3(64,32),B,0,stream>>>(Kdec, Kdec, Vtdec, gdec, ctx, 1);
    gemm_kernel<<<dim3(64,8,1),B,0,stream>>>(ctx, wOdt, dec_bo, tmp,  4096, 512,  512, 0, 0, 0, 0, 0);
    ln_kernel<<<dim3(4096),B,0,stream>>>(tmp, y, hbuf, h_bf);
    // encoder-decoder stage
    gemm_kernel<<<dim3(64,1,8),B,0,stream>>>(z_bf, wKet, enc_bk, Kenc,  4096,  64,  512, 0, 64*512, 64, 2, 0);
    gemm_kernel<<<dim3(64,1,8),B,0,stream>>>(z_bf, wVet, enc_bv, Vtenc, 4096,  64,  512, 0, 64*512, 64, 3, 0);
    gemm_kernel<<<dim3(64,1,8),B,0,stream>>>(h_bf, wQet, enc_bq, Qenc,  4096,  64,  512, 0, 64*512, 64, 2, 0);
    attn_kernel<<<dim3(64,32),B,0,stream>>>(Qenc, Kenc, Vtenc, genc, ctx, 0);
    gemm_kernel<<<dim3(64,8,1),B,0,stream>>>(ctx, wOet, enc_bo, tmp,  4096, 512,  512, 0, 0, 0, 0, 0);
    ln_kernel<<<dim3(4096),B,0,stream>>>(tmp, hbuf, h2, h2_bf);
    // MLP
    gemm_kernel<<<dim3(64,32,1),B,0,stream>>>(h2_bf, wF1t, fc_b1, fc1, 4096, 2048,  512, 0, 0, 0, 1, 1);
    gemm_kernel<<<dim3(64,8,1), B,0,stream>>>(fc1,  wF2t, fc_b2, tmp, 4096,  512, 2048, 0, 0, 0, 0, 0);
    ln_kernel<<<dim3(4096),B,0,stream>>>(tmp, h2, outp, (short*)0);
}

// Round 3
// 726.456 us; speedup vs baseline: 1.1108x; 1.1108x over previous
//
#include <hip/hip_runtime.h>
#include <stdint.h>

typedef short short8 __attribute__((ext_vector_type(8)));
typedef short short4v __attribute__((ext_vector_type(4)));
typedef float floatx4 __attribute__((ext_vector_type(4)));

#define H_  8
#define NB_ 4      // batch N
#define S_  1024
#define D_  512
#define KD_ 64

__device__ __forceinline__ short f2bf(float f){
    unsigned u = __builtin_bit_cast(unsigned, f);
    u += 0x7fffu + ((u>>16)&1u);
    return (short)(u>>16);
}
__device__ __forceinline__ float wred_addf(float x){
    #pragma unroll
    for(int o=32;o>0;o>>=1) x += __shfl_xor(x,o,64);
    return x;
}
__device__ __forceinline__ float wred_maxf(float x){
    #pragma unroll
    for(int o=32;o>0;o>>=1) x = fmaxf(x,__shfl_xor(x,o,64));
    return x;
}

// ---------------- elementwise fp32 -> bf16 ----------------
__global__ __launch_bounds__(256) void cvt_bf16_kernel(const float* __restrict__ in,
                                                       short* __restrict__ out, int n){
    int i = (blockIdx.x*256 + threadIdx.x)*4;
    if (i + 3 < n){
        floatx4 v = *(const floatx4*)(in + i);
        short4v r;
        #pragma unroll
        for(int j=0;j<4;j++) r[j] = f2bf(v[j]);
        *(short4v*)(out + i) = r;
    }
}

// ---------------- weight transpose + convert: in [R][C] f32 -> out [C][R] bf16 ----------------
__global__ __launch_bounds__(256) void wtrans_kernel(const float* __restrict__ in, short* __restrict__ out,
                                                     int R, int C, long inB, long outB){
    __shared__ float t[32][33];
    int z = blockIdx.z;
    const float* ip = in + (long)z*inB;
    short* op = out + (long)z*outB;
    int c0 = blockIdx.x*32, r0 = blockIdx.y*32;
    int tid = threadIdx.x;
    int r = tid>>3, cq = (tid&7)*4;
    #pragma unroll
    for(int i=0;i<4;i++) t[r][cq+i] = ip[(long)(r0+r)*C + c0+cq+i];
    __syncthreads();
    int c = tid>>3, rq = (tid&7)*4;
    #pragma unroll
    for(int i=0;i<4;i++) op[(long)(c0+c)*R + r0+rq+i] = f2bf(t[rq+i][c]);
}

// ---------------- row softmax of the two graphs ----------------
__global__ __launch_bounds__(256) void graph_softmax_kernel(const float* __restrict__ g0,
                                                            const float* __restrict__ g1,
                                                            float* __restrict__ o0,
                                                            float* __restrict__ o1){
    int row = blockIdx.x;
    const float* g = blockIdx.y ? g1 : g0;
    float* o = blockIdx.y ? o1 : o0;
    const float* gr = g + (long)row*S_;
    float* orow = o + (long)row*S_;
    int tid = threadIdx.x, wave = tid>>6, lane = tid&63;
    __shared__ float red[8];
    float v[4]; float mx = -3.0e38f;
    #pragma unroll
    for(int i=0;i<4;i++){ v[i] = gr[tid + 256*i]; mx = fmaxf(mx, v[i]); }
    mx = wred_maxf(mx);
    if(lane==0) red[wave] = mx;
    __syncthreads();
    mx = fmaxf(fmaxf(red[0],red[1]), fmaxf(red[2],red[3]));
    float s = 0.f;
    #pragma unroll
    for(int i=0;i<4;i++){ v[i] = __expf(v[i]-mx); s += v[i]; }
    s = wred_addf(s);
    if(lane==0) red[4+wave] = s;
    __syncthreads();
    s = red[4]+red[5]+red[6]+red[7];
    float inv = 1.f/s;
    #pragma unroll
    for(int i=0;i<4;i++) orow[tid + 256*i] = v[i]*inv;
}

// ---------------- generic bf16 MFMA GEMM: C = A[MxK] * Bt[NxK]^T + bias ----------------
__global__ __launch_bounds__(256) void gemm_kernel(
    const short* __restrict__ A, const short* __restrict__ Bt, const float* __restrict__ bias,
    void* __restrict__ out, int M, int N, int K,
    long batchA, long batchB, long batchBias, int mode, int relu)
{
    int z = blockIdx.z;
    const short* Ab = A + (long)z*batchA;
    const short* Bb = Bt + (long)z*batchB;
    const float* bb = bias + (long)z*batchBias;
    int m0 = blockIdx.x*64, n0 = blockIdx.y*64;
    int tid = threadIdx.x, wave = tid>>6, lane = tid&63;
    int quad = lane>>4, nl = lane&15;
    int wm = (wave&1)*32, wn = (wave>>1)*32;
    floatx4 acc[2][2];
    #pragma unroll
    for(int i=0;i<2;i++)
        #pragma unroll
        for(int j=0;j<2;j++) acc[i][j] = (floatx4){0.f,0.f,0.f,0.f};

    const short* Aptr0 = Ab + (long)(m0 + wm + nl)*K + quad*8;
    const short* Aptr1 = Aptr0 + 16*(long)K;
    const short* Bptr0 = Bb + (long)(n0 + wn + nl)*K + quad*8;
    const short* Bptr1 = Bptr0 + 16*(long)K;

    for(int k0=0;k0<K;k0+=32){
        short8 a0 = *(const short8*)(Aptr0 + k0);
        short8 a1 = *(const short8*)(Aptr1 + k0);
        short8 b0 = *(const short8*)(Bptr0 + k0);
        short8 b1 = *(const short8*)(Bptr1 + k0);
        acc[0][0] = __builtin_amdgcn_mfma_f32_16x16x32_bf16(a0,b0,acc[0][0],0,0,0);
        acc[0][1] = __builtin_amdgcn_mfma_f32_16x16x32_bf16(a0,b1,acc[0][1],0,0,0);
        acc[1][0] = __builtin_amdgcn_mfma_f32_16x16x32_bf16(a1,b0,acc[1][0],0,0,0);
        acc[1][1] = __builtin_amdgcn_mfma_f32_16x16x32_bf16(a1,b1,acc[1][1],0,0,0);
    }
    #pragma unroll
    for(int i=0;i<2;i++){
        #pragma unroll
        for(int j=0;j<2;j++){
            int n = n0 + wn + j*16 + nl;
            float bv = bb[n];
            #pragma unroll
            for(int r=0;r<4;r++){
                int m = m0 + wm + i*16 + quad*4 + r;
                float v = acc[i][j][r] + bv;
                if(relu) v = fmaxf(v, 0.f);
                if(mode==0)      ((float*)out)[(long)m*N + n] = v;
                else if(mode==1) ((short*)out)[(long)m*N + n] = f2bf(v);
                else if(mode==2) ((short*)out)[ ((long)(z*NB_ + (m>>10))*S_ + (m&1023))*KD_ + n ] = f2bf(v);
                else             ((short*)out)[ ((long)(z*NB_ + (m>>10))*KD_ + n)*S_ + (m&1023) ] = f2bf(v);
            }
        }
    }
}

// ---------------- fused attention ----------------
// Qb/Kb: bf16 [HN][S][64]; Vt: bf16 [HN][64][S]; graph: softmaxed [S][S] f32
// ctx out: bf16 [(n*S + q)*512 + h*64 + v]
// LDS rows rotated by 4*q floats: phase1 writes 2-way (free), phase2 conflict-free,
// phase3 b128 reads spread evenly over all 8 4-bank clusters. Phase3 p1 base must
// be wrapped independently: cs is only 4-aligned, so cs+4 can cross the row end.
__global__ __launch_bounds__(256) void attn_kernel(
    const short* __restrict__ Qb, const short* __restrict__ Kb, const short* __restrict__ Vt,
    const float* __restrict__ graph, short* __restrict__ ctx, int causal)
{
    __shared__ float sc[16*1024];   // 64 KiB
    int qt = blockIdx.x, hn = blockIdx.y;
    int h = hn>>2, n = hn&3;
    int q0 = qt*16;
    int tid=threadIdx.x, wave=tid>>6, lane=tid&63, quad=lane>>4, nl=lane&15;

    // ---- phase 1: scores = Q K^T / 8 into LDS ----
    const short* Qp = Qb + ((long)hn*S_ + q0 + nl)*KD_ + quad*8;
    short8 aq0 = *(const short8*)(Qp);
    short8 aq1 = *(const short8*)(Qp + 32);
    const short* Kp = Kb + (long)hn*S_*KD_;
    int stmax = causal ? qt : 63;
    for(int st=wave; st<=stmax; st+=4){
        const short* kp = Kp + (st*16 + nl)*KD_ + quad*8;
        short8 b0 = *(const short8*)(kp);
        short8 b1 = *(const short8*)(kp + 32);
        floatx4 c = (floatx4){0.f,0.f,0.f,0.f};
        c = __builtin_amdgcn_mfma_f32_16x16x32_bf16(aq0,b0,c,0,0,0);
        c = __builtin_amdgcn_mfma_f32_16x16x32_bf16(aq1,b1,c,0,0,0);
        #pragma unroll
        for(int r=0;r<4;r++){
            int q = quad*4 + r, s = st*16 + nl;
            sc[q*1024 + ((s + q*4)&1023)] = c[r]*0.125f;
        }
    }
    __syncthreads();

    // ---- phase 2: 4 rows per wave, ILP-4 interleaved exact top-128 + softmax + blend ----
    {
        int qb = wave*4;
        float v[4][16]; unsigned mv[4][16]; float g[4][16];
        float mx[4];
        // prefetch graph rows (global) early
        #pragma unroll
        for(int r=0;r<4;r++){
            const float* grow = graph + (long)(q0 + qb + r)*S_;
            #pragma unroll
            for(int j=0;j<16;j++) g[r][j] = grow[lane + 64*j];
        }
        #pragma unroll
        for(int r=0;r<4;r++){
            int q = qb + r;
            int slimit = causal ? (q0 + q) : 1023;
            float m = -3.0e38f;
            #pragma unroll
            for(int j=0;j<16;j++){
                int s = lane + 64*j;
                float x = (s<=slimit) ? sc[q*1024 + ((s + q*4)&1023)] : -__builtin_inff();
                v[r][j] = x; m = fmaxf(m,x);
                unsigned u = __builtin_bit_cast(unsigned, x);
                mv[r][j] = (u>>31) ? ~u : (u | 0x80000000u);
            }
            mx[r] = m;
        }
        #pragma unroll
        for(int o=32;o>0;o>>=1){
            #pragma unroll
            for(int r=0;r<4;r++) mx[r] = fmaxf(mx[r], __shfl_xor(mx[r],o,64));
        }
        unsigned lo[4], hi[4];
        #pragma unroll
        for(int r=0;r<4;r++){
            unsigned um = __builtin_bit_cast(unsigned, mx[r]);
            um = (um>>31) ? ~um : (um | 0x80000000u);
            lo[r] = 0u; hi[r] = um + 1u;
        }
        while( ((hi[0]-lo[0])>1u) | ((hi[1]-lo[1])>1u) | ((hi[2]-lo[2])>1u) | ((hi[3]-lo[3])>1u) ){
            unsigned mid[4]; int act[4];
            #pragma unroll
            for(int r=0;r<4;r++){ act[r] = ((hi[r]-lo[r])>1u); mid[r] = lo[r] + ((hi[r]-lo[r])>>1); }
            unsigned p0=0u, p1=0u;
            #pragma unroll
            for(int j=0;j<16;j++){
                p0 += (unsigned)(mv[0][j]>=mid[0]) + ((unsigned)(mv[1][j]>=mid[1])<<16);
                p1 += (unsigned)(mv[2][j]>=mid[2]) + ((unsigned)(mv[3][j]>=mid[3])<<16);
            }
            #pragma unroll
            for(int o=32;o>0;o>>=1){ p0 += __shfl_xor(p0,o,64); p1 += __shfl_xor(p1,o,64); }
            unsigned c[4] = { p0&0xffffu, p0>>16, p1&0xffffu, p1>>16 };
            #pragma unroll
            for(int r=0;r<4;r++){
                if(act[r]){
                    if(c[r] >= 128u){ lo[r] = mid[r]; if(c[r] == 128u) hi[r] = mid[r]+1u; }
                    else hi[r] = mid[r];
                }
            }
        }
        // exp + sum (reuse v[] for exp values)
        float sm[4];
        #pragma unroll
        for(int r=0;r<4;r++){
            float s_ = 0.f;
            #pragma unroll
            for(int j=0;j<16;j++){
                float ee = (mv[r][j] >= lo[r]) ? __expf(v[r][j]-mx[r]) : 0.f;
                v[r][j] = ee; s_ += ee;
            }
            sm[r] = s_;
        }
        #pragma unroll
        for(int o=32;o>0;o>>=1){
            #pragma unroll
            for(int r=0;r<4;r++) sm[r] += __shfl_xor(sm[r],o,64);
        }
        #pragma unroll
        for(int r=0;r<4;r++){
            int q = qb + r;
            float inv = 0.5f/sm[r];   // (1-gw) = 0.5
            #pragma unroll
            for(int j=0;j<16;j++){
                int s = lane + 64*j;
                sc[q*1024 + ((s + q*4)&1023)] = 0.5f*g[r][j] + v[r][j]*inv;
            }
        }
    }
    __syncthreads();

    // ---- phase 3: ctx = att @ V  (full s-range; graph part everywhere) ----
    int v0 = wave*16;
    const short* Vp = Vt + ((long)hn*KD_ + v0 + nl)*S_;
    floatx4 o4 = (floatx4){0.f,0.f,0.f,0.f};
    int qrow = nl;
    for(int s0=0; s0<1024; s0+=32){
        int cs = (s0 + quad*8 + qrow*4) & 1023;
        floatx4 p0 = *(floatx4*)(&sc[qrow*1024 + cs]);
        floatx4 p1 = *(floatx4*)(&sc[qrow*1024 + ((cs + 4)&1023)]);
        short8 ap;
        #pragma unroll
        for(int j=0;j<4;j++){ ap[j] = f2bf(p0[j]); ap[j+4] = f2bf(p1[j]); }
        short8 bv = *(const short8*)(Vp + s0 + quad*8);
        o4 = __builtin_amdgcn_mfma_f32_16x16x32_bf16(ap,bv,o4,0,0,0);
    }
    #pragma unroll
    for(int r=0;r<4;r++){
        int q = quad*4 + r;
        ctx[ ((long)(n*S_ + q0 + q))*512 + h*KD_ + v0 + nl ] = f2bf(o4[r]);
    }
}

// ---------------- LayerNorm(x + res), optional f32 + bf16 outputs ----------------
__global__ __launch_bounds__(256) void ln_kernel(const float* __restrict__ x, const float* __restrict__ res,
                                                 float* __restrict__ outf, short* __restrict__ outb){
    long row = blockIdx.x;
    const float* xr = x + row*D_;
    const float* rr = res + row*D_;
    int tid = threadIdx.x, wave = tid>>6, lane = tid&63;
    float t0 = xr[tid] + rr[tid];
    float t1 = xr[tid+256] + rr[tid+256];
    float s = t0 + t1, s2 = t0*t0 + t1*t1;
    __shared__ float red[8];
    s = wred_addf(s); s2 = wred_addf(s2);
    if(lane==0){ red[wave] = s; red[4+wave] = s2; }
    __syncthreads();
    s  = red[0]+red[1]+red[2]+red[3];
    s2 = red[4]+red[5]+red[6]+red[7];
    float mean = s*(1.f/512.f);
    float var = s2*(1.f/512.f) - mean*mean;
    float rs = rsqrtf(var + 1e-5f);
    float o0 = (t0-mean)*rs, o1 = (t1-mean)*rs;
    if(outf){ outf[row*D_+tid] = o0; outf[row*D_+tid+256] = o1; }
    if(outb){ outb[row*D_+tid] = f2bf(o0); outb[row*D_+tid+256] = f2bf(o1); }
}

extern "C" void kernel_launch(void* const* d_in, const int* in_sizes, int n_in,
                              void* d_out, int out_size, void* d_ws, size_t ws_size,
                              hipStream_t stream)
{
    const float* z         = (const float*)d_in[0];
    const float* y         = (const float*)d_in[1];
    const float* graph_dec = (const float*)d_in[2];
    const float* graph_enc = (const float*)d_in[3];
    const float* dec_Wk = (const float*)d_in[4];  const float* dec_bk = (const float*)d_in[5];
    const float* dec_Wv = (const float*)d_in[6];  const float* dec_bv = (const float*)d_in[7];
    const float* dec_Wo = (const float*)d_in[8];  const float* dec_bo = (const float*)d_in[9];
    const float* enc_Wk = (const float*)d_in[10]; const float* enc_bk = (const float*)d_in[11];
    const float* enc_Wq = (const float*)d_in[12]; const float* enc_bq = (const float*)d_in[13];
    const float* enc_Wv = (const float*)d_in[14]; const float* enc_bv = (const float*)d_in[15];
    const float* enc_Wo = (const float*)d_in[16]; const float* enc_bo = (const float*)d_in[17];
    const float* fc_W1  = (const float*)d_in[18]; const float* fc_b1  = (const float*)d_in[19];
    const float* fc_W2  = (const float*)d_in[20]; const float* fc_b2  = (const float*)d_in[21];

    char* ws = (char*)d_ws;
    float* gdec  = (float*)(ws + 0x0000000);
    float* genc  = (float*)(ws + 0x0400000);
    short* y_bf  = (short*)(ws + 0x0800000);
    short* z_bf  = (short*)(ws + 0x0C00000);
    short* Kdec  = (short*)(ws + 0x1000000);
    short* Vtdec = (short*)(ws + 0x1400000);
    short* Kenc  = (short*)(ws + 0x1800000);
    short* Vtenc = (short*)(ws + 0x1C00000);
    short* Qenc  = (short*)(ws + 0x2000000);
    short* ctx   = (short*)(ws + 0x2400000);
    float* tmp   = (float*)(ws + 0x2800000);
    float* hbuf  = (float*)(ws + 0x3000000);
    short* h_bf  = (short*)(ws + 0x3800000);
    float* h2    = (float*)(ws + 0x3C00000);
    short* h2_bf = (short*)(ws + 0x4400000);
    short* fc1   = (short*)(ws + 0x4800000);
    short* wKdt  = (short*)(ws + 0x5800000);
    short* wVdt  = (short*)(ws + 0x5880000);
    short* wOdt  = (short*)(ws + 0x5900000);
    short* wKet  = (short*)(ws + 0x5980000);
    short* wQet  = (short*)(ws + 0x5A00000);
    short* wVet  = (short*)(ws + 0x5A80000);
    short* wOet  = (short*)(ws + 0x5B00000);
    short* wF1t  = (short*)(ws + 0x5B80000);
    short* wF2t  = (short*)(ws + 0x5D80000);
    float* outp  = (float*)d_out;

    dim3 B(256);
    // weight transposes -> bf16 [N][K]
    wtrans_kernel<<<dim3(2,16,8),  B,0,stream>>>(dec_Wk, wKdt, 512,  64, 512*64, 64*512);
    wtrans_kernel<<<dim3(2,16,8),  B,0,stream>>>(dec_Wv, wVdt, 512,  64, 512*64, 64*512);
    wtrans_kernel<<<dim3(16,16,1), B,0,stream>>>(dec_Wo, wOdt, 512, 512, 0, 0);
    wtrans_kernel<<<dim3(2,16,8),  B,0,stream>>>(enc_Wk, wKet, 512,  64, 512*64, 64*512);
    wtrans_kernel<<<dim3(2,16,8),  B,0,stream>>>(enc_Wq, wQet, 512,  64, 512*64, 64*512);
    wtrans_kernel<<<dim3(2,16,8),  B,0,stream>>>(enc_Wv, wVet, 512,  64, 512*64, 64*512);
    wtrans_kernel<<<dim3(16,16,1), B,0,stream>>>(enc_Wo, wOet, 512, 512, 0, 0);
    wtrans_kernel<<<dim3(64,16,1), B,0,stream>>>(fc_W1,  wF1t, 512,2048, 0, 0);
    wtrans_kernel<<<dim3(16,64,1), B,0,stream>>>(fc_W2,  wF2t,2048, 512, 0, 0);
    // activation converts
    cvt_bf16_kernel<<<dim3(2048),B,0,stream>>>(y, y_bf, 2097152);
    cvt_bf16_kernel<<<dim3(2048),B,0,stream>>>(z, z_bf, 2097152);
    // graph softmax
    graph_softmax_kernel<<<dim3(1024,2),B,0,stream>>>(graph_dec, graph_enc, gdec, genc);
    // decoder stage
    gemm_kernel<<<dim3(64,1,8),B,0,stream>>>(y_bf, wKdt, dec_bk, Kdec,  4096,  64,  512, 0, 64*512, 64, 2, 0);
    gemm_kernel<<<dim3(64,1,8),B,0,stream>>>(y_bf, wVdt, dec_bv, Vtdec, 4096,  64,  512, 0, 64*512, 64, 3, 0);
    attn_kernel<<<dim3(64,32),B,0,stream>>>(Kdec, Kdec, Vtdec, gdec, ctx, 1);
    gemm_kernel<<<dim3(64,8,1),B,0,stream>>>(ctx, wOdt, dec_bo, tmp,  4096, 512,  512, 0, 0, 0, 0, 0);
    ln_kernel<<<dim3(4096),B,0,stream>>>(tmp, y, hbuf, h_bf);
    // encoder-decoder stage
    gemm_kernel<<<dim3(64,1,8),B,0,stream>>>(z_bf, wKet, enc_bk, Kenc,  4096,  64,  512, 0, 64*512, 64, 2, 0);
    gemm_kernel<<<dim3(64,1,8),B,0,stream>>>(z_bf, wVet, enc_bv, Vtenc, 4096,  64,  512, 0, 64*512, 64, 3, 0);
    gemm_kernel<<<dim3(64,1,8),B,0,stream>>>(h_bf, wQet, enc_bq, Qenc,  4096,  64,  512, 0, 64*512, 64, 2, 0);
    attn_kernel<<<dim3(64,32),B,0,stream>>>(Qenc, Kenc, Vtenc, genc, ctx, 0);
    gemm_kernel<<<dim3(64,8,1),B,0,stream>>>(ctx, wOet, enc_bo, tmp,  4096, 512,  512, 0, 0, 0, 0, 0);
    ln_kernel<<<dim3(4096),B,0,stream>>>(tmp, hbuf, h2, h2_bf);
    // MLP
    gemm_kernel<<<dim3(64,32,1),B,0,stream>>>(h2_bf, wF1t, fc_b1, fc1, 4096, 2048,  512, 0, 0, 0, 1, 1);
    gemm_kernel<<<dim3(64,8,1), B,0,stream>>>(fc1,  wF2t, fc_b2, tmp, 4096,  512, 2048, 0, 0, 0, 0, 0);
    ln_kernel<<<dim3(4096),B,0,stream>>>(tmp, h2, outp, (short*)0);
}

// Round 4
// 671.715 us; speedup vs baseline: 1.2013x; 1.0815x over previous
//
#include <hip/hip_runtime.h>
#include <stdint.h>

typedef short short8 __attribute__((ext_vector_type(8)));
typedef short short4v __attribute__((ext_vector_type(4)));
typedef float floatx4 __attribute__((ext_vector_type(4)));

#define H_  8
#define NB_ 4      // batch N
#define S_  1024
#define D_  512
#define KD_ 64

__device__ __forceinline__ short f2bf(float f){
    unsigned u = __builtin_bit_cast(unsigned, f);
    u += 0x7fffu + ((u>>16)&1u);
    return (short)(u>>16);
}
__device__ __forceinline__ float wred_addf(float x){
    #pragma unroll
    for(int o=32;o>0;o>>=1) x += __shfl_xor(x,o,64);
    return x;
}
__device__ __forceinline__ float wred_maxf(float x){
    #pragma unroll
    for(int o=32;o>0;o>>=1) x = fmaxf(x,__shfl_xor(x,o,64));
    return x;
}

// ---------------- elementwise fp32 -> bf16 ----------------
__global__ __launch_bounds__(256) void cvt_bf16_kernel(const float* __restrict__ in,
                                                       short* __restrict__ out, int n){
    int i = (blockIdx.x*256 + threadIdx.x)*4;
    if (i + 3 < n){
        floatx4 v = *(const floatx4*)(in + i);
        short4v r;
        #pragma unroll
        for(int j=0;j<4;j++) r[j] = f2bf(v[j]);
        *(short4v*)(out + i) = r;
    }
}

// ---------------- weight transpose + convert: in [R][C] f32 -> out [C][R] bf16 ----------------
__global__ __launch_bounds__(256) void wtrans_kernel(const float* __restrict__ in, short* __restrict__ out,
                                                     int R, int C, long inB, long outB){
    __shared__ float t[32][33];
    int z = blockIdx.z;
    const float* ip = in + (long)z*inB;
    short* op = out + (long)z*outB;
    int c0 = blockIdx.x*32, r0 = blockIdx.y*32;
    int tid = threadIdx.x;
    int r = tid>>3, cq = (tid&7)*4;
    #pragma unroll
    for(int i=0;i<4;i++) t[r][cq+i] = ip[(long)(r0+r)*C + c0+cq+i];
    __syncthreads();
    int c = tid>>3, rq = (tid&7)*4;
    #pragma unroll
    for(int i=0;i<4;i++) op[(long)(c0+c)*R + r0+rq+i] = f2bf(t[rq+i][c]);
}

// ---------------- row softmax of the two graphs ----------------
__global__ __launch_bounds__(256) void graph_softmax_kernel(const float* __restrict__ g0,
                                                            const float* __restrict__ g1,
                                                            float* __restrict__ o0,
                                                            float* __restrict__ o1){
    int row = blockIdx.x;
    const float* g = blockIdx.y ? g1 : g0;
    float* o = blockIdx.y ? o1 : o0;
    const float* gr = g + (long)row*S_;
    float* orow = o + (long)row*S_;
    int tid = threadIdx.x, wave = tid>>6, lane = tid&63;
    __shared__ float red[8];
    float v[4]; float mx = -3.0e38f;
    #pragma unroll
    for(int i=0;i<4;i++){ v[i] = gr[tid + 256*i]; mx = fmaxf(mx, v[i]); }
    mx = wred_maxf(mx);
    if(lane==0) red[wave] = mx;
    __syncthreads();
    mx = fmaxf(fmaxf(red[0],red[1]), fmaxf(red[2],red[3]));
    float s = 0.f;
    #pragma unroll
    for(int i=0;i<4;i++){ v[i] = __expf(v[i]-mx); s += v[i]; }
    s = wred_addf(s);
    if(lane==0) red[4+wave] = s;
    __syncthreads();
    s = red[4]+red[5]+red[6]+red[7];
    float inv = 1.f/s;
    #pragma unroll
    for(int i=0;i<4;i++) orow[tid + 256*i] = v[i]*inv;
}

// ---------------- small bf16 MFMA GEMM (direct-global), used for N=64 projections ----------------
// mode 2: bf16 K/Q layout out[((z*4 + m>>10)*1024 + (m&1023))*64 + n]   (N==64)
// mode 3: bf16 Vt layout  out[((z*4 + m>>10)*64 + n)*1024 + (m&1023)]  (N==64)
__global__ __launch_bounds__(256) void gemm_kernel(
    const short* __restrict__ A, const short* __restrict__ Bt, const float* __restrict__ bias,
    void* __restrict__ out, int M, int N, int K,
    long batchA, long batchB, long batchBias, int mode, int relu)
{
    int z = blockIdx.z;
    const short* Ab = A + (long)z*batchA;
    const short* Bb = Bt + (long)z*batchB;
    const float* bb = bias + (long)z*batchBias;
    int m0 = blockIdx.x*64, n0 = blockIdx.y*64;
    int tid = threadIdx.x, wave = tid>>6, lane = tid&63;
    int quad = lane>>4, nl = lane&15;
    int wm = (wave&1)*32, wn = (wave>>1)*32;
    floatx4 acc[2][2];
    #pragma unroll
    for(int i=0;i<2;i++)
        #pragma unroll
        for(int j=0;j<2;j++) acc[i][j] = (floatx4){0.f,0.f,0.f,0.f};

    const short* Aptr0 = Ab + (long)(m0 + wm + nl)*K + quad*8;
    const short* Aptr1 = Aptr0 + 16*(long)K;
    const short* Bptr0 = Bb + (long)(n0 + wn + nl)*K + quad*8;
    const short* Bptr1 = Bptr0 + 16*(long)K;

    for(int k0=0;k0<K;k0+=32){
        short8 a0 = *(const short8*)(Aptr0 + k0);
        short8 a1 = *(const short8*)(Aptr1 + k0);
        short8 b0 = *(const short8*)(Bptr0 + k0);
        short8 b1 = *(const short8*)(Bptr1 + k0);
        acc[0][0] = __builtin_amdgcn_mfma_f32_16x16x32_bf16(a0,b0,acc[0][0],0,0,0);
        acc[0][1] = __builtin_amdgcn_mfma_f32_16x16x32_bf16(a0,b1,acc[0][1],0,0,0);
        acc[1][0] = __builtin_amdgcn_mfma_f32_16x16x32_bf16(a1,b0,acc[1][0],0,0,0);
        acc[1][1] = __builtin_amdgcn_mfma_f32_16x16x32_bf16(a1,b1,acc[1][1],0,0,0);
    }
    #pragma unroll
    for(int i=0;i<2;i++){
        #pragma unroll
        for(int j=0;j<2;j++){
            int n = n0 + wn + j*16 + nl;
            float bv = bb[n];
            #pragma unroll
            for(int r=0;r<4;r++){
                int m = m0 + wm + i*16 + quad*4 + r;
                float v = acc[i][j][r] + bv;
                if(relu) v = fmaxf(v, 0.f);
                if(mode==0)      ((float*)out)[(long)m*N + n] = v;
                else if(mode==1) ((short*)out)[(long)m*N + n] = f2bf(v);
                else if(mode==2) ((short*)out)[ ((long)(z*NB_ + (m>>10))*S_ + (m&1023))*KD_ + n ] = f2bf(v);
                else             ((short*)out)[ ((long)(z*NB_ + (m>>10))*KD_ + n)*S_ + (m&1023) ] = f2bf(v);
            }
        }
    }
}

// ---------------- big MFMA GEMM, m97 pattern: LDS staging via global_load_lds(16B) ----------------
// A [M][K] bf16, Bt [N][K] bf16, out = A*Bt^T + bias. TM in {64,128}, TN=128.
template<int TM, int TN, int OUTBF, int RELU>
__global__ __launch_bounds__(256) void gemm_big_kernel(
    const short* __restrict__ A, const short* __restrict__ Bt, const float* __restrict__ bias,
    void* __restrict__ out, int M, int N, int K)
{
    __shared__ short As[TM*32];
    __shared__ short Bs[TN*32];
    int m0 = blockIdx.x*TM, n0 = blockIdx.y*TN;
    int tid = threadIdx.x, wave = tid>>6, lane = tid&63, quad = lane>>4, nl = lane&15;
    constexpr int MI = TM/32, NI = TN/32;
    int wm = (wave&1)*(TM/2), wn = (wave>>1)*(TN/2);
    floatx4 acc[MI][NI];
    #pragma unroll
    for(int i=0;i<MI;i++)
        #pragma unroll
        for(int j=0;j<NI;j++) acc[i][j] = (floatx4){0.f,0.f,0.f,0.f};

    int r = tid>>2, c = (tid&3)*8;      // staging coords: 64 rows per 256-thread instr
    for(int k0=0;k0<K;k0+=32){
        __syncthreads();
        #pragma unroll
        for(int i=0;i<TM/64;i++)
            __builtin_amdgcn_global_load_lds(
                (const __attribute__((address_space(1))) unsigned*)(A + (long)(m0 + r + i*64)*K + k0 + c),
                (__attribute__((address_space(3))) unsigned*)((char*)As + i*4096 + wave*1024),
                16, 0, 0);
        #pragma unroll
        for(int i=0;i<TN/64;i++)
            __builtin_amdgcn_global_load_lds(
                (const __attribute__((address_space(1))) unsigned*)(Bt + (long)(n0 + r + i*64)*K + k0 + c),
                (__attribute__((address_space(3))) unsigned*)((char*)Bs + i*4096 + wave*1024),
                16, 0, 0);
        __syncthreads();
        short8 af[MI], bfr[NI];
        #pragma unroll
        for(int i=0;i<MI;i++) af[i] = *(const short8*)(As + (wm + i*16 + nl)*32 + quad*8);
        #pragma unroll
        for(int j=0;j<NI;j++) bfr[j] = *(const short8*)(Bs + (wn + j*16 + nl)*32 + quad*8);
        #pragma unroll
        for(int i=0;i<MI;i++)
            #pragma unroll
            for(int j=0;j<NI;j++)
                acc[i][j] = __builtin_amdgcn_mfma_f32_16x16x32_bf16(af[i],bfr[j],acc[i][j],0,0,0);
    }
    #pragma unroll
    for(int j=0;j<NI;j++){
        int n = n0 + wn + j*16 + nl;
        float bv = bias[n];
        #pragma unroll
        for(int i=0;i<MI;i++){
            #pragma unroll
            for(int rr=0;rr<4;rr++){
                int m = m0 + wm + i*16 + quad*4 + rr;
                float v = acc[i][j][rr] + bv;
                if(RELU) v = fmaxf(v, 0.f);
                if(OUTBF) ((short*)out)[(long)m*N + n] = f2bf(v);
                else      ((float*)out)[(long)m*N + n] = v;
            }
        }
    }
}

// ---------------- fused attention ----------------
// Qb/Kb: bf16 [HN][S][64]; Vt: bf16 [HN][64][S]; graph: softmaxed [S][S] f32
// ctx out: bf16 [(n*S + q)*512 + h*64 + v]
// Scores f32 in sc (rot 4*q). After score->reg load (+barrier), phase 2 writes the
// blended att as bf16 into the low 32KB of sc (rot 8*q, 16B-aligned for phase-3 b128).
// Top-128: exact bit-space bisection; counts via __ballot+__popcll (SALU), control uniform.
__global__ __launch_bounds__(256) void attn_kernel(
    const short* __restrict__ Qb, const short* __restrict__ Kb, const short* __restrict__ Vt,
    const float* __restrict__ graph, short* __restrict__ ctx, int causal)
{
    __shared__ float sc[16*1024];   // 64 KiB
    int qt = blockIdx.x, hn = blockIdx.y;
    int h = hn>>2, n = hn&3;
    int q0 = qt*16;
    int tid=threadIdx.x, wave=tid>>6, lane=tid&63, quad=lane>>4, nl=lane&15;

    // ---- phase 1: scores = Q K^T / 8 into LDS (f32, rot 4q) ----
    const short* Qp = Qb + ((long)hn*S_ + q0 + nl)*KD_ + quad*8;
    short8 aq0 = *(const short8*)(Qp);
    short8 aq1 = *(const short8*)(Qp + 32);
    const short* Kp = Kb + (long)hn*S_*KD_;
    int stmax = causal ? qt : 63;
    for(int st=wave; st<=stmax; st+=4){
        const short* kp = Kp + (st*16 + nl)*KD_ + quad*8;
        short8 b0 = *(const short8*)(kp);
        short8 b1 = *(const short8*)(kp + 32);
        floatx4 cc = (floatx4){0.f,0.f,0.f,0.f};
        cc = __builtin_amdgcn_mfma_f32_16x16x32_bf16(aq0,b0,cc,0,0,0);
        cc = __builtin_amdgcn_mfma_f32_16x16x32_bf16(aq1,b1,cc,0,0,0);
        #pragma unroll
        for(int rr=0;rr<4;rr++){
            int q = quad*4 + rr, s = st*16 + nl;
            sc[q*1024 + ((s + q*4)&1023)] = cc[rr]*0.125f;
        }
    }
    __syncthreads();

    // ---- phase 2 ----
    short* attb = (short*)sc;   // bf16 att, rows of 1024 shorts, rot 8q (low 32KB)
    {
        int qb = wave*4;
        unsigned mv[4][16];
        float g[4][16];
        float mx[4];
        // prefetch graph rows (global, in flight during search)
        #pragma unroll
        for(int rr=0;rr<4;rr++){
            const float* grow = graph + (long)(q0 + qb + rr)*S_;
            #pragma unroll
            for(int j=0;j<16;j++) g[rr][j] = grow[lane + 64*j];
        }
        // load scores -> monotone 32-bit keys
        #pragma unroll
        for(int rr=0;rr<4;rr++){
            int q = qb + rr;
            int slimit = causal ? (q0 + q) : 1023;
            float m = -3.0e38f;
            #pragma unroll
            for(int j=0;j<16;j++){
                int s = lane + 64*j;
                float x = (s<=slimit) ? sc[q*1024 + ((s + q*4)&1023)] : -__builtin_inff();
                m = fmaxf(m, x);
                unsigned u = __builtin_bit_cast(unsigned, x);
                mv[rr][j] = (u>>31) ? ~u : (u | 0x80000000u);
            }
            mx[rr] = m;
        }
        __syncthreads();   // all waves have their scores in regs; sc low half may be overwritten
        #pragma unroll
        for(int o=32;o>0;o>>=1){
            #pragma unroll
            for(int rr=0;rr<4;rr++) mx[rr] = fmaxf(mx[rr], __shfl_xor(mx[rr],o,64));
        }
        unsigned lo[4], hi[4];
        #pragma unroll
        for(int rr=0;rr<4;rr++){
            unsigned um = __builtin_bit_cast(unsigned, mx[rr]);
            um = (um>>31) ? ~um : (um | 0x80000000u);
            lo[rr] = 0u; hi[rr] = um + 1u;
        }
        // exact bisection; counts on the scalar pipe (ballot+popcount), no shuffles
        while( ((hi[0]-lo[0])>1u) | ((hi[1]-lo[1])>1u) | ((hi[2]-lo[2])>1u) | ((hi[3]-lo[3])>1u) ){
            #pragma unroll
            for(int rr=0;rr<4;rr++){
                if(hi[rr]-lo[rr] > 1u){
                    unsigned mid = lo[rr] + ((hi[rr]-lo[rr])>>1);
                    unsigned cnt = 0u;
                    #pragma unroll
                    for(int j=0;j<16;j++) cnt += (unsigned)__popcll(__ballot(mv[rr][j] >= mid));
                    if(cnt >= 128u){ lo[rr] = mid; if(cnt == 128u) hi[rr] = mid + 1u; }
                    else hi[rr] = mid;
                }
            }
        }
        // exp + sum; reconstruct float from key (2 ops)
        float e[4][16]; float sm[4];
        #pragma unroll
        for(int rr=0;rr<4;rr++){
            float s_ = 0.f;
            #pragma unroll
            for(int j=0;j<16;j++){
                unsigned k = mv[rr][j];
                unsigned u = (k>>31) ? (k & 0x7fffffffu) : ~k;
                float x = __builtin_bit_cast(float, u);
                float ee = (k >= lo[rr]) ? __expf(x - mx[rr]) : 0.f;
                e[rr][j] = ee; s_ += ee;
            }
            sm[rr] = s_;
        }
        #pragma unroll
        for(int o=32;o>0;o>>=1){
            #pragma unroll
            for(int rr=0;rr<4;rr++) sm[rr] += __shfl_xor(sm[rr],o,64);
        }
        #pragma unroll
        for(int rr=0;rr<4;rr++){
            int q = qb + rr;
            float inv = 0.5f/sm[rr];   // (1-gw) = 0.5
            #pragma unroll
            for(int j=0;j<16;j++){
                int s = lane + 64*j;
                attb[q*1024 + ((s + q*8)&1023)] = f2bf(0.5f*g[rr][j] + e[rr][j]*inv);
            }
        }
    }
    __syncthreads();

    // ---- phase 3: ctx = att @ V  (bf16 att straight from LDS, one b128/step) ----
    int v0 = wave*16;
    const short* Vp = Vt + ((long)hn*KD_ + v0 + nl)*S_;
    floatx4 o4 = (floatx4){0.f,0.f,0.f,0.f};
    int qrow = nl;
    for(int s0=0; s0<1024; s0+=32){
        int cs = (s0 + quad*8 + qrow*8) & 1023;
        short8 ap = *(const short8*)(attb + qrow*1024 + cs);
        short8 bv = *(const short8*)(Vp + s0 + quad*8);
        o4 = __builtin_amdgcn_mfma_f32_16x16x32_bf16(ap,bv,o4,0,0,0);
    }
    #pragma unroll
    for(int rr=0;rr<4;rr++){
        int q = quad*4 + rr;
        ctx[ ((long)(n*S_ + q0 + q))*512 + h*KD_ + v0 + nl ] = f2bf(o4[rr]);
    }
}

// ---------------- LayerNorm(x + res), optional f32 + bf16 outputs ----------------
__global__ __launch_bounds__(256) void ln_kernel(const float* __restrict__ x, const float* __restrict__ res,
                                                 float* __restrict__ outf, short* __restrict__ outb){
    long row = blockIdx.x;
    const float* xr = x + row*D_;
    const float* rr = res + row*D_;
    int tid = threadIdx.x, wave = tid>>6, lane = tid&63;
    float t0 = xr[tid] + rr[tid];
    float t1 = xr[tid+256] + rr[tid+256];
    float s = t0 + t1, s2 = t0*t0 + t1*t1;
    __shared__ float red[8];
    s = wred_addf(s); s2 = wred_addf(s2);
    if(lane==0){ red[wave] = s; red[4+wave] = s2; }
    __syncthreads();
    s  = red[0]+red[1]+red[2]+red[3];
    s2 = red[4]+red[5]+red[6]+red[7];
    float mean = s*(1.f/512.f);
    float var = s2*(1.f/512.f) - mean*mean;
    float rs = rsqrtf(var + 1e-5f);
    float o0 = (t0-mean)*rs, o1 = (t1-mean)*rs;
    if(outf){ outf[row*D_+tid] = o0; outf[row*D_+tid+256] = o1; }
    if(outb){ outb[row*D_+tid] = f2bf(o0); outb[row*D_+tid+256] = f2bf(o1); }
}

extern "C" void kernel_launch(void* const* d_in, const int* in_sizes, int n_in,
                              void* d_out, int out_size, void* d_ws, size_t ws_size,
                              hipStream_t stream)
{
    const float* z         = (const float*)d_in[0];
    const float* y         = (const float*)d_in[1];
    const float* graph_dec = (const float*)d_in[2];
    const float* graph_enc = (const float*)d_in[3];
    const float* dec_Wk = (const float*)d_in[4];  const float* dec_bk = (const float*)d_in[5];
    const float* dec_Wv = (const float*)d_in[6];  const float* dec_bv = (const float*)d_in[7];
    const float* dec_Wo = (const float*)d_in[8];  const float* dec_bo = (const float*)d_in[9];
    const float* enc_Wk = (const float*)d_in[10]; const float* enc_bk = (const float*)d_in[11];
    const float* enc_Wq = (const float*)d_in[12]; const float* enc_bq = (const float*)d_in[13];
    const float* enc_Wv = (const float*)d_in[14]; const float* enc_bv = (const float*)d_in[15];
    const float* enc_Wo = (const float*)d_in[16]; const float* enc_bo = (const float*)d_in[17];
    const float* fc_W1  = (const float*)d_in[18]; const float* fc_b1  = (const float*)d_in[19];
    const float* fc_W2  = (const float*)d_in[20]; const float* fc_b2  = (const float*)d_in[21];

    char* ws = (char*)d_ws;
    float* gdec  = (float*)(ws + 0x0000000);
    float* genc  = (float*)(ws + 0x0400000);
    short* y_bf  = (short*)(ws + 0x0800000);
    short* z_bf  = (short*)(ws + 0x0C00000);
    short* Kdec  = (short*)(ws + 0x1000000);
    short* Vtdec = (short*)(ws + 0x1400000);
    short* Kenc  = (short*)(ws + 0x1800000);
    short* Vtenc = (short*)(ws + 0x1C00000);
    short* Qenc  = (short*)(ws + 0x2000000);
    short* ctx   = (short*)(ws + 0x2400000);
    float* tmp   = (float*)(ws + 0x2800000);
    float* hbuf  = (float*)(ws + 0x3000000);
    short* h_bf  = (short*)(ws + 0x3800000);
    float* h2    = (float*)(ws + 0x3C00000);
    short* h2_bf = (short*)(ws + 0x4400000);
    short* fc1   = (short*)(ws + 0x4800000);
    short* wKdt  = (short*)(ws + 0x5800000);
    short* wVdt  = (short*)(ws + 0x5880000);
    short* wOdt  = (short*)(ws + 0x5900000);
    short* wKet  = (short*)(ws + 0x5980000);
    short* wQet  = (short*)(ws + 0x5A00000);
    short* wVet  = (short*)(ws + 0x5A80000);
    short* wOet  = (short*)(ws + 0x5B00000);
    short* wF1t  = (short*)(ws + 0x5B80000);
    short* wF2t  = (short*)(ws + 0x5D80000);
    float* outp  = (float*)d_out;

    dim3 B(256);
    // weight transposes -> bf16 [N][K]
    wtrans_kernel<<<dim3(2,16,8),  B,0,stream>>>(dec_Wk, wKdt, 512,  64, 512*64, 64*512);
    wtrans_kernel<<<dim3(2,16,8),  B,0,stream>>>(dec_Wv, wVdt, 512,  64, 512*64, 64*512);
    wtrans_kernel<<<dim3(16,16,1), B,0,stream>>>(dec_Wo, wOdt, 512, 512, 0, 0);
    wtrans_kernel<<<dim3(2,16,8),  B,0,stream>>>(enc_Wk, wKet, 512,  64, 512*64, 64*512);
    wtrans_kernel<<<dim3(2,16,8),  B,0,stream>>>(enc_Wq, wQet, 512,  64, 512*64, 64*512);
    wtrans_kernel<<<dim3(2,16,8),  B,0,stream>>>(enc_Wv, wVet, 512,  64, 512*64, 64*512);
    wtrans_kernel<<<dim3(16,16,1), B,0,stream>>>(enc_Wo, wOet, 512, 512, 0, 0);
    wtrans_kernel<<<dim3(64,16,1), B,0,stream>>>(fc_W1,  wF1t, 512,2048, 0, 0);
    wtrans_kernel<<<dim3(16,64,1), B,0,stream>>>(fc_W2,  wF2t,2048, 512, 0, 0);
    // activation converts
    cvt_bf16_kernel<<<dim3(2048),B,0,stream>>>(y, y_bf, 2097152);
    cvt_bf16_kernel<<<dim3(2048),B,0,stream>>>(z, z_bf, 2097152);
    // graph softmax
    graph_softmax_kernel<<<dim3(1024,2),B,0,stream>>>(graph_dec, graph_enc, gdec, genc);
    // decoder stage
    gemm_kernel<<<dim3(64,1,8),B,0,stream>>>(y_bf, wKdt, dec_bk, Kdec,  4096,  64,  512, 0, 64*512, 64, 2, 0);
    gemm_kernel<<<dim3(64,1,8),B,0,stream>>>(y_bf, wVdt, dec_bv, Vtdec, 4096,  64,  512, 0, 64*512, 64, 3, 0);
    attn_kernel<<<dim3(64,32),B,0,stream>>>(Kdec, Kdec, Vtdec, gdec, ctx, 1);
    gemm_big_kernel<64,128,0,0><<<dim3(64,4),B,0,stream>>>(ctx, wOdt, dec_bo, tmp, 4096, 512, 512);
    ln_kernel<<<dim3(4096),B,0,stream>>>(tmp, y, hbuf, h_bf);
    // encoder-decoder stage
    gemm_kernel<<<dim3(64,1,8),B,0,stream>>>(z_bf, wKet, enc_bk, Kenc,  4096,  64,  512, 0, 64*512, 64, 2, 0);
    gemm_kernel<<<dim3(64,1,8),B,0,stream>>>(z_bf, wVet, enc_bv, Vtenc, 4096,  64,  512, 0, 64*512, 64, 3, 0);
    gemm_kernel<<<dim3(64,1,8),B,0,stream>>>(h_bf, wQet, enc_bq, Qenc,  4096,  64,  512, 0, 64*512, 64, 2, 0);
    attn_kernel<<<dim3(64,32),B,0,stream>>>(Qenc, Kenc, Vtenc, genc, ctx, 0);
    gemm_big_kernel<64,128,0,0><<<dim3(64,4),B,0,stream>>>(ctx, wOet, enc_bo, tmp, 4096, 512, 512);
    ln_kernel<<<dim3(4096),B,0,stream>>>(tmp, hbuf, h2, h2_bf);
    // MLP
    gemm_big_kernel<128,128,1,1><<<dim3(32,16),B,0,stream>>>(h2_bf, wF1t, fc_b1, fc1, 4096, 2048, 512);
    gemm_big_kernel<64,128,0,0><<<dim3(64,4),B,0,stream>>>(fc1, wF2t, fc_b2, tmp, 4096, 512, 2048);
    ln_kernel<<<dim3(4096),B,0,stream>>>(tmp, h2, outp, (short*)0);
}

// Round 5
// 648.956 us; speedup vs baseline: 1.2434x; 1.0351x over previous
//
#include <hip/hip_runtime.h>
#include <stdint.h>

typedef short short8 __attribute__((ext_vector_type(8)));
typedef short short4v __attribute__((ext_vector_type(4)));
typedef float floatx4 __attribute__((ext_vector_type(4)));

#define H_  8
#define NB_ 4      // batch N
#define S_  1024
#define D_  512
#define KD_ 64

__device__ __forceinline__ short f2bf(float f){
    unsigned u = __builtin_bit_cast(unsigned, f);
    u += 0x7fffu + ((u>>16)&1u);
    return (short)(u>>16);
}
__device__ __forceinline__ float wred_addf(float x){
    #pragma unroll
    for(int o=32;o>0;o>>=1) x += __shfl_xor(x,o,64);
    return x;
}
__device__ __forceinline__ float wred_maxf(float x){
    #pragma unroll
    for(int o=32;o>0;o>>=1) x = fmaxf(x,__shfl_xor(x,o,64));
    return x;
}

// ---------------- elementwise fp32 -> bf16 ----------------
__global__ __launch_bounds__(256) void cvt_bf16_kernel(const float* __restrict__ in,
                                                       short* __restrict__ out, int n){
    int i = (blockIdx.x*256 + threadIdx.x)*4;
    if (i + 3 < n){
        floatx4 v = *(const floatx4*)(in + i);
        short4v r;
        #pragma unroll
        for(int j=0;j<4;j++) r[j] = f2bf(v[j]);
        *(short4v*)(out + i) = r;
    }
}

// ---------------- weight transpose + convert: in [R][C] f32 -> out [C][R] bf16 ----------------
__global__ __launch_bounds__(256) void wtrans_kernel(const float* __restrict__ in, short* __restrict__ out,
                                                     int R, int C, long inB, long outB){
    __shared__ float t[32][33];
    int z = blockIdx.z;
    const float* ip = in + (long)z*inB;
    short* op = out + (long)z*outB;
    int c0 = blockIdx.x*32, r0 = blockIdx.y*32;
    int tid = threadIdx.x;
    int r = tid>>3, cq = (tid&7)*4;
    #pragma unroll
    for(int i=0;i<4;i++) t[r][cq+i] = ip[(long)(r0+r)*C + c0+cq+i];
    __syncthreads();
    int c = tid>>3, rq = (tid&7)*4;
    #pragma unroll
    for(int i=0;i<4;i++) op[(long)(c0+c)*R + r0+rq+i] = f2bf(t[rq+i][c]);
}

// ---------------- row softmax of the two graphs ----------------
__global__ __launch_bounds__(256) void graph_softmax_kernel(const float* __restrict__ g0,
                                                            const float* __restrict__ g1,
                                                            float* __restrict__ o0,
                                                            float* __restrict__ o1){
    int row = blockIdx.x;
    const float* g = blockIdx.y ? g1 : g0;
    float* o = blockIdx.y ? o1 : o0;
    const float* gr = g + (long)row*S_;
    float* orow = o + (long)row*S_;
    int tid = threadIdx.x, wave = tid>>6, lane = tid&63;
    __shared__ float red[8];
    float v[4]; float mx = -3.0e38f;
    #pragma unroll
    for(int i=0;i<4;i++){ v[i] = gr[tid + 256*i]; mx = fmaxf(mx, v[i]); }
    mx = wred_maxf(mx);
    if(lane==0) red[wave] = mx;
    __syncthreads();
    mx = fmaxf(fmaxf(red[0],red[1]), fmaxf(red[2],red[3]));
    float s = 0.f;
    #pragma unroll
    for(int i=0;i<4;i++){ v[i] = __expf(v[i]-mx); s += v[i]; }
    s = wred_addf(s);
    if(lane==0) red[4+wave] = s;
    __syncthreads();
    s = red[4]+red[5]+red[6]+red[7];
    float inv = 1.f/s;
    #pragma unroll
    for(int i=0;i<4;i++) orow[tid + 256*i] = v[i]*inv;
}

// ---------------- small bf16 MFMA GEMM (direct-global), used for N=64 projections ----------------
// mode 2: bf16 K/Q layout out[((z*4 + m>>10)*1024 + (m&1023))*64 + n]   (N==64)
// mode 3: bf16 Vt layout  out[((z*4 + m>>10)*64 + n)*1024 + (m&1023)]  (N==64)
__global__ __launch_bounds__(256) void gemm_kernel(
    const short* __restrict__ A, const short* __restrict__ Bt, const float* __restrict__ bias,
    void* __restrict__ out, int M, int N, int K,
    long batchA, long batchB, long batchBias, int mode, int relu)
{
    int z = blockIdx.z;
    const short* Ab = A + (long)z*batchA;
    const short* Bb = Bt + (long)z*batchB;
    const float* bb = bias + (long)z*batchBias;
    int m0 = blockIdx.x*64, n0 = blockIdx.y*64;
    int tid = threadIdx.x, wave = tid>>6, lane = tid&63;
    int quad = lane>>4, nl = lane&15;
    int wm = (wave&1)*32, wn = (wave>>1)*32;
    floatx4 acc[2][2];
    #pragma unroll
    for(int i=0;i<2;i++)
        #pragma unroll
        for(int j=0;j<2;j++) acc[i][j] = (floatx4){0.f,0.f,0.f,0.f};

    const short* Aptr0 = Ab + (long)(m0 + wm + nl)*K + quad*8;
    const short* Aptr1 = Aptr0 + 16*(long)K;
    const short* Bptr0 = Bb + (long)(n0 + wn + nl)*K + quad*8;
    const short* Bptr1 = Bptr0 + 16*(long)K;

    for(int k0=0;k0<K;k0+=32){
        short8 a0 = *(const short8*)(Aptr0 + k0);
        short8 a1 = *(const short8*)(Aptr1 + k0);
        short8 b0 = *(const short8*)(Bptr0 + k0);
        short8 b1 = *(const short8*)(Bptr1 + k0);
        acc[0][0] = __builtin_amdgcn_mfma_f32_16x16x32_bf16(a0,b0,acc[0][0],0,0,0);
        acc[0][1] = __builtin_amdgcn_mfma_f32_16x16x32_bf16(a0,b1,acc[0][1],0,0,0);
        acc[1][0] = __builtin_amdgcn_mfma_f32_16x16x32_bf16(a1,b0,acc[1][0],0,0,0);
        acc[1][1] = __builtin_amdgcn_mfma_f32_16x16x32_bf16(a1,b1,acc[1][1],0,0,0);
    }
    #pragma unroll
    for(int i=0;i<2;i++){
        #pragma unroll
        for(int j=0;j<2;j++){
            int n = n0 + wn + j*16 + nl;
            float bv = bb[n];
            #pragma unroll
            for(int r=0;r<4;r++){
                int m = m0 + wm + i*16 + quad*4 + r;
                float v = acc[i][j][r] + bv;
                if(relu) v = fmaxf(v, 0.f);
                if(mode==0)      ((float*)out)[(long)m*N + n] = v;
                else if(mode==1) ((short*)out)[(long)m*N + n] = f2bf(v);
                else if(mode==2) ((short*)out)[ ((long)(z*NB_ + (m>>10))*S_ + (m&1023))*KD_ + n ] = f2bf(v);
                else             ((short*)out)[ ((long)(z*NB_ + (m>>10))*KD_ + n)*S_ + (m&1023) ] = f2bf(v);
            }
        }
    }
}

// ---------------- big MFMA GEMM, m97 pattern: LDS staging via global_load_lds(16B) ----------------
template<int TM, int TN, int OUTBF, int RELU>
__global__ __launch_bounds__(256) void gemm_big_kernel(
    const short* __restrict__ A, const short* __restrict__ Bt, const float* __restrict__ bias,
    void* __restrict__ out, int M, int N, int K)
{
    __shared__ short As[TM*32];
    __shared__ short Bs[TN*32];
    int m0 = blockIdx.x*TM, n0 = blockIdx.y*TN;
    int tid = threadIdx.x, wave = tid>>6, lane = tid&63, quad = lane>>4, nl = lane&15;
    constexpr int MI = TM/32, NI = TN/32;
    int wm = (wave&1)*(TM/2), wn = (wave>>1)*(TN/2);
    floatx4 acc[MI][NI];
    #pragma unroll
    for(int i=0;i<MI;i++)
        #pragma unroll
        for(int j=0;j<NI;j++) acc[i][j] = (floatx4){0.f,0.f,0.f,0.f};

    int r = tid>>2, c = (tid&3)*8;      // staging coords: 64 rows per 256-thread instr
    for(int k0=0;k0<K;k0+=32){
        __syncthreads();
        #pragma unroll
        for(int i=0;i<TM/64;i++)
            __builtin_amdgcn_global_load_lds(
                (const __attribute__((address_space(1))) unsigned*)(A + (long)(m0 + r + i*64)*K + k0 + c),
                (__attribute__((address_space(3))) unsigned*)((char*)As + i*4096 + wave*1024),
                16, 0, 0);
        #pragma unroll
        for(int i=0;i<TN/64;i++)
            __builtin_amdgcn_global_load_lds(
                (const __attribute__((address_space(1))) unsigned*)(Bt + (long)(n0 + r + i*64)*K + k0 + c),
                (__attribute__((address_space(3))) unsigned*)((char*)Bs + i*4096 + wave*1024),
                16, 0, 0);
        __syncthreads();
        short8 af[MI], bfr[NI];
        #pragma unroll
        for(int i=0;i<MI;i++) af[i] = *(const short8*)(As + (wm + i*16 + nl)*32 + quad*8);
        #pragma unroll
        for(int j=0;j<NI;j++) bfr[j] = *(const short8*)(Bs + (wn + j*16 + nl)*32 + quad*8);
        #pragma unroll
        for(int i=0;i<MI;i++)
            #pragma unroll
            for(int j=0;j<NI;j++)
                acc[i][j] = __builtin_amdgcn_mfma_f32_16x16x32_bf16(af[i],bfr[j],acc[i][j],0,0,0);
    }
    #pragma unroll
    for(int j=0;j<NI;j++){
        int n = n0 + wn + j*16 + nl;
        float bv = bias[n];
        #pragma unroll
        for(int i=0;i<MI;i++){
            #pragma unroll
            for(int rr=0;rr<4;rr++){
                int m = m0 + wm + i*16 + quad*4 + rr;
                float v = acc[i][j][rr] + bv;
                if(RELU) v = fmaxf(v, 0.f);
                if(OUTBF) ((short*)out)[(long)m*N + n] = f2bf(v);
                else      ((float*)out)[(long)m*N + n] = v;
            }
        }
    }
}

// ---------------- fused attention (8 q-rows per block, 32 KiB LDS, 5 blocks/CU) ----------------
// Qb/Kb: bf16 [HN][S][64]; Vt: bf16 [HN][64][S]; graph: softmaxed [S][S] f32
// ctx out: bf16 [(n*S + q)*512 + h*64 + v]
// Scores f32 rows 0..7 in sc (rot 4q). Phase 2: 2 rows/wave, exact bisection, counts
// packed 2x16-bit in one u32 -> ONE shuffle chain/iter. att bf16 overwrites low 16 KiB
// (rot 8q) after a barrier. Phase 1/3 MFMA use duplicated A rows (nl&7), writes guarded.
__global__ __launch_bounds__(256) void attn_kernel(
    const short* __restrict__ Qb, const short* __restrict__ Kb, const short* __restrict__ Vt,
    const float* __restrict__ graph, short* __restrict__ ctx, int causal)
{
    __shared__ float sc[8*1024];   // 32 KiB
    int qt = blockIdx.x, hn = blockIdx.y;
    int h = hn>>2, n = hn&3;
    int q0 = qt*8;
    int tid=threadIdx.x, wave=tid>>6, lane=tid&63, quad=lane>>4, nl=lane&15;

    // ---- phase 1: scores = Q K^T / 8 into LDS (f32, rot 4q), rows duplicated 8..15 ----
    const short* Qp = Qb + ((long)hn*S_ + q0 + (nl&7))*KD_ + quad*8;
    short8 aq0 = *(const short8*)(Qp);
    short8 aq1 = *(const short8*)(Qp + 32);
    const short* Kp = Kb + (long)hn*S_*KD_;
    int stmax = causal ? ((q0+7)>>4) : 63;
    for(int st=wave; st<=stmax; st+=4){
        const short* kp = Kp + (st*16 + nl)*KD_ + quad*8;
        short8 b0 = *(const short8*)(kp);
        short8 b1 = *(const short8*)(kp + 32);
        floatx4 cc = (floatx4){0.f,0.f,0.f,0.f};
        cc = __builtin_amdgcn_mfma_f32_16x16x32_bf16(aq0,b0,cc,0,0,0);
        cc = __builtin_amdgcn_mfma_f32_16x16x32_bf16(aq1,b1,cc,0,0,0);
        #pragma unroll
        for(int rr=0;rr<4;rr++){
            int q = quad*4 + rr, s = st*16 + nl;
            if(q < 8) sc[q*1024 + ((s + q*4)&1023)] = cc[rr]*0.125f;
        }
    }
    __syncthreads();

    // ---- phase 2: 2 rows/wave ----
    short* attb = (short*)sc;   // bf16 att, 8 rows of 1024 shorts, rot 8q (low 16KB)
    {
        int qb = wave*2;
        unsigned mv[2][16];
        float g[2][16];
        float mx[2];
        // graph prefetch (in flight during search)
        #pragma unroll
        for(int rr=0;rr<2;rr++){
            const float* grow = graph + (long)(q0 + qb + rr)*S_;
            #pragma unroll
            for(int j=0;j<16;j++) g[rr][j] = grow[lane + 64*j];
        }
        // scores -> monotone keys
        #pragma unroll
        for(int rr=0;rr<2;rr++){
            int q = qb + rr;
            int slimit = causal ? (q0 + q) : 1023;
            float m = -3.0e38f;
            #pragma unroll
            for(int j=0;j<16;j++){
                int s = lane + 64*j;
                float x = (s<=slimit) ? sc[q*1024 + ((s + q*4)&1023)] : -__builtin_inff();
                m = fmaxf(m, x);
                unsigned u = __builtin_bit_cast(unsigned, x);
                mv[rr][j] = (u>>31) ? ~u : (u | 0x80000000u);
            }
            mx[rr] = m;
        }
        __syncthreads();   // scores now in regs everywhere; sc low half can be overwritten
        #pragma unroll
        for(int o=32;o>0;o>>=1){
            #pragma unroll
            for(int rr=0;rr<2;rr++) mx[rr] = fmaxf(mx[rr], __shfl_xor(mx[rr],o,64));
        }
        unsigned lo[2], hi[2];
        #pragma unroll
        for(int rr=0;rr<2;rr++){
            unsigned um = __builtin_bit_cast(unsigned, mx[rr]);
            um = (um>>31) ? ~um : (um | 0x80000000u);
            lo[rr] = 0u; hi[rr] = um + 1u;
        }
        // exact bisection, both rows per iteration, counts packed in one u32
        while( ((hi[0]-lo[0])>1u) | ((hi[1]-lo[1])>1u) ){
            unsigned mid0 = lo[0] + ((hi[0]-lo[0])>>1);
            unsigned mid1 = lo[1] + ((hi[1]-lo[1])>>1);
            unsigned p = 0u;
            #pragma unroll
            for(int j=0;j<16;j++)
                p += (unsigned)(mv[0][j]>=mid0) + ((unsigned)(mv[1][j]>=mid1)<<16);
            #pragma unroll
            for(int o=32;o>0;o>>=1) p += __shfl_xor(p,o,64);
            unsigned c0 = p & 0xffffu, c1 = p >> 16;
            if(hi[0]-lo[0] > 1u){
                if(c0 >= 128u){ lo[0] = mid0; if(c0 == 128u) hi[0] = mid0 + 1u; }
                else hi[0] = mid0;
            }
            if(hi[1]-lo[1] > 1u){
                if(c1 >= 128u){ lo[1] = mid1; if(c1 == 128u) hi[1] = mid1 + 1u; }
                else hi[1] = mid1;
            }
        }
        // exp + sum; e overwrites mv storage (bit-cast) to cap VGPRs
        float sm[2];
        #pragma unroll
        for(int rr=0;rr<2;rr++){
            float s_ = 0.f;
            #pragma unroll
            for(int j=0;j<16;j++){
                unsigned k = mv[rr][j];
                unsigned u = (k>>31) ? (k & 0x7fffffffu) : ~k;
                float x = __builtin_bit_cast(float, u);
                float ee = (k >= lo[rr]) ? __expf(x - mx[rr]) : 0.f;
                mv[rr][j] = __builtin_bit_cast(unsigned, ee);
                s_ += ee;
            }
            sm[rr] = s_;
        }
        #pragma unroll
        for(int o=32;o>0;o>>=1){
            #pragma unroll
            for(int rr=0;rr<2;rr++) sm[rr] += __shfl_xor(sm[rr],o,64);
        }
        #pragma unroll
        for(int rr=0;rr<2;rr++){
            int q = qb + rr;
            float inv = 0.5f/sm[rr];   // (1-gw) = 0.5
            #pragma unroll
            for(int j=0;j<16;j++){
                int s = lane + 64*j;
                float ee = __builtin_bit_cast(float, mv[rr][j]);
                attb[q*1024 + ((s + q*8)&1023)] = f2bf(0.5f*g[rr][j] + ee*inv);
            }
        }
    }
    __syncthreads();

    // ---- phase 3: ctx = att @ V (rows duplicated, writes guarded) ----
    int v0 = wave*16;
    const short* Vp = Vt + ((long)hn*KD_ + v0 + nl)*S_;
    floatx4 o4 = (floatx4){0.f,0.f,0.f,0.f};
    int qrow = nl & 7;
    for(int s0=0; s0<1024; s0+=32){
        int cs = (s0 + quad*8 + qrow*8) & 1023;
        short8 ap = *(const short8*)(attb + qrow*1024 + cs);
        short8 bv = *(const short8*)(Vp + s0 + quad*8);
        o4 = __builtin_amdgcn_mfma_f32_16x16x32_bf16(ap,bv,o4,0,0,0);
    }
    #pragma unroll
    for(int rr=0;rr<4;rr++){
        int q = quad*4 + rr;
        if(q < 8)
            ctx[ ((long)(n*S_ + q0 + q))*512 + h*KD_ + v0 + nl ] = f2bf(o4[rr]);
    }
}

// ---------------- LayerNorm(x + res), optional f32 + bf16 outputs ----------------
__global__ __launch_bounds__(256) void ln_kernel(const float* __restrict__ x, const float* __restrict__ res,
                                                 float* __restrict__ outf, short* __restrict__ outb){
    long row = blockIdx.x;
    const float* xr = x + row*D_;
    const float* rr = res + row*D_;
    int tid = threadIdx.x, wave = tid>>6, lane = tid&63;
    float t0 = xr[tid] + rr[tid];
    float t1 = xr[tid+256] + rr[tid+256];
    float s = t0 + t1, s2 = t0*t0 + t1*t1;
    __shared__ float red[8];
    s = wred_addf(s); s2 = wred_addf(s2);
    if(lane==0){ red[wave] = s; red[4+wave] = s2; }
    __syncthreads();
    s  = red[0]+red[1]+red[2]+red[3];
    s2 = red[4]+red[5]+red[6]+red[7];
    float mean = s*(1.f/512.f);
    float var = s2*(1.f/512.f) - mean*mean;
    float rs = rsqrtf(var + 1e-5f);
    float o0 = (t0-mean)*rs, o1 = (t1-mean)*rs;
    if(outf){ outf[row*D_+tid] = o0; outf[row*D_+tid+256] = o1; }
    if(outb){ outb[row*D_+tid] = f2bf(o0); outb[row*D_+tid+256] = f2bf(o1); }
}

extern "C" void kernel_launch(void* const* d_in, const int* in_sizes, int n_in,
                              void* d_out, int out_size, void* d_ws, size_t ws_size,
                              hipStream_t stream)
{
    const float* z         = (const float*)d_in[0];
    const float* y         = (const float*)d_in[1];
    const float* graph_dec = (const float*)d_in[2];
    const float* graph_enc = (const float*)d_in[3];
    const float* dec_Wk = (const float*)d_in[4];  const float* dec_bk = (const float*)d_in[5];
    const float* dec_Wv = (const float*)d_in[6];  const float* dec_bv = (const float*)d_in[7];
    const float* dec_Wo = (const float*)d_in[8];  const float* dec_bo = (const float*)d_in[9];
    const float* enc_Wk = (const float*)d_in[10]; const float* enc_bk = (const float*)d_in[11];
    const float* enc_Wq = (const float*)d_in[12]; const float* enc_bq = (const float*)d_in[13];
    const float* enc_Wv = (const float*)d_in[14]; const float* enc_bv = (const float*)d_in[15];
    const float* enc_Wo = (const float*)d_in[16]; const float* enc_bo = (const float*)d_in[17];
    const float* fc_W1  = (const float*)d_in[18]; const float* fc_b1  = (const float*)d_in[19];
    const float* fc_W2  = (const float*)d_in[20]; const float* fc_b2  = (const float*)d_in[21];

    char* ws = (char*)d_ws;
    float* gdec  = (float*)(ws + 0x0000000);
    float* genc  = (float*)(ws + 0x0400000);
    short* y_bf  = (short*)(ws + 0x0800000);
    short* z_bf  = (short*)(ws + 0x0C00000);
    short* Kdec  = (short*)(ws + 0x1000000);
    short* Vtdec = (short*)(ws + 0x1400000);
    short* Kenc  = (short*)(ws + 0x1800000);
    short* Vtenc = (short*)(ws + 0x1C00000);
    short* Qenc  = (short*)(ws + 0x2000000);
    short* ctx   = (short*)(ws + 0x2400000);
    float* tmp   = (float*)(ws + 0x2800000);
    float* hbuf  = (float*)(ws + 0x3000000);
    short* h_bf  = (short*)(ws + 0x3800000);
    float* h2    = (float*)(ws + 0x3C00000);
    short* h2_bf = (short*)(ws + 0x4400000);
    short* fc1   = (short*)(ws + 0x4800000);
    short* wKdt  = (short*)(ws + 0x5800000);
    short* wVdt  = (short*)(ws + 0x5880000);
    short* wOdt  = (short*)(ws + 0x5900000);
    short* wKet  = (short*)(ws + 0x5980000);
    short* wQet  = (short*)(ws + 0x5A00000);
    short* wVet  = (short*)(ws + 0x5A80000);
    short* wOet  = (short*)(ws + 0x5B00000);
    short* wF1t  = (short*)(ws + 0x5B80000);
    short* wF2t  = (short*)(ws + 0x5D80000);
    float* outp  = (float*)d_out;

    dim3 B(256);
    // weight transposes -> bf16 [N][K]
    wtrans_kernel<<<dim3(2,16,8),  B,0,stream>>>(dec_Wk, wKdt, 512,  64, 512*64, 64*512);
    wtrans_kernel<<<dim3(2,16,8),  B,0,stream>>>(dec_Wv, wVdt, 512,  64, 512*64, 64*512);
    wtrans_kernel<<<dim3(16,16,1), B,0,stream>>>(dec_Wo, wOdt, 512, 512, 0, 0);
    wtrans_kernel<<<dim3(2,16,8),  B,0,stream>>>(enc_Wk, wKet, 512,  64, 512*64, 64*512);
    wtrans_kernel<<<dim3(2,16,8),  B,0,stream>>>(enc_Wq, wQet, 512,  64, 512*64, 64*512);
    wtrans_kernel<<<dim3(2,16,8),  B,0,stream>>>(enc_Wv, wVet, 512,  64, 512*64, 64*512);
    wtrans_kernel<<<dim3(16,16,1), B,0,stream>>>(enc_Wo, wOet, 512, 512, 0, 0);
    wtrans_kernel<<<dim3(64,16,1), B,0,stream>>>(fc_W1,  wF1t, 512,2048, 0, 0);
    wtrans_kernel<<<dim3(16,64,1), B,0,stream>>>(fc_W2,  wF2t,2048, 512, 0, 0);
    // activation converts
    cvt_bf16_kernel<<<dim3(2048),B,0,stream>>>(y, y_bf, 2097152);
    cvt_bf16_kernel<<<dim3(2048),B,0,stream>>>(z, z_bf, 2097152);
    // graph softmax
    graph_softmax_kernel<<<dim3(1024,2),B,0,stream>>>(graph_dec, graph_enc, gdec, genc);
    // decoder stage
    gemm_kernel<<<dim3(64,1,8),B,0,stream>>>(y_bf, wKdt, dec_bk, Kdec,  4096,  64,  512, 0, 64*512, 64, 2, 0);
    gemm_kernel<<<dim3(64,1,8),B,0,stream>>>(y_bf, wVdt, dec_bv, Vtdec, 4096,  64,  512, 0, 64*512, 64, 3, 0);
    attn_kernel<<<dim3(128,32),B,0,stream>>>(Kdec, Kdec, Vtdec, gdec, ctx, 1);
    gemm_big_kernel<64,128,0,0><<<dim3(64,4),B,0,stream>>>(ctx, wOdt, dec_bo, tmp, 4096, 512, 512);
    ln_kernel<<<dim3(4096),B,0,stream>>>(tmp, y, hbuf, h_bf);
    // encoder-decoder stage
    gemm_kernel<<<dim3(64,1,8),B,0,stream>>>(z_bf, wKet, enc_bk, Kenc,  4096,  64,  512, 0, 64*512, 64, 2, 0);
    gemm_kernel<<<dim3(64,1,8),B,0,stream>>>(z_bf, wVet, enc_bv, Vtenc, 4096,  64,  512, 0, 64*512, 64, 3, 0);
    gemm_kernel<<<dim3(64,1,8),B,0,stream>>>(h_bf, wQet, enc_bq, Qenc,  4096,  64,  512, 0, 64*512, 64, 2, 0);
    attn_kernel<<<dim3(128,32),B,0,stream>>>(Qenc, Kenc, Vtenc, genc, ctx, 0);
    gemm_big_kernel<64,128,0,0><<<dim3(64,4),B,0,stream>>>(ctx, wOet, enc_bo, tmp, 4096, 512, 512);
    ln_kernel<<<dim3(4096),B,0,stream>>>(tmp, hbuf, h2, h2_bf);
    // MLP
    gemm_big_kernel<128,128,1,1><<<dim3(32,16),B,0,stream>>>(h2_bf, wF1t, fc_b1, fc1, 4096, 2048, 512);
    gemm_big_kernel<64,128,0,0><<<dim3(64,4),B,0,stream>>>(fc1, wF2t, fc_b2, tmp, 4096, 512, 2048);
    ln_kernel<<<dim3(4096),B,0,stream>>>(tmp, h2, outp, (short*)0);
}